// Round 4
// baseline (571.097 us; speedup 1.0000x reference)
//
#include <hip/hip_runtime.h>
#include <hip/hip_bf16.h>

#define CDIM 256
#define EPS 1e-5f
#define SLOPE 0.01f

using f32x4  = __attribute__((ext_vector_type(4))) float;
typedef __bf16 bf16x8 __attribute__((ext_vector_type(8)));

// ---------------- workspace layout ----------------
enum : size_t {
  OFF_WS_HF   = 0,
  OFF_WS_LF   = 9216,
  OFF_WP_HF   = 20480,
  OFF_BS_HF   = 21504,
  OFF_WP_LF   = 22528,
  OFF_BS_LF   = 23552,
  OFF_MEAN_HF = 24576,
  OFF_RSTD_HF = 25600,
  OFF_MEAN_LF = 26624,
  OFF_RSTD_LF = 27648,
  OFF_U16     = 32768,          // start of ushort region (float units)
};
// ushort offsets relative to u16 base
enum : size_t {
  U_YH  = 0,          // [4][128][128][256] bf16
  U_YL  = 16777216,   // [4][64][64][256]
  U_HFA = 20971520,   // [4][128][128][256]
  U_LFA = 37748736,   // [4][64][64][256]
  U_HFP = 41943040,   // [4][64][64][256]
  U_PK  = 46137344,   // 6 packed weights, each 589824
  PK_SZ = 589824,
  U_END = U_PK + 6 * PK_SZ,
};
enum : size_t { TOTAL_F = OFF_U16 + (U_END + 1) / 2 };

__device__ float g_scratch[TOTAL_F];

__device__ __forceinline__ int refl(int q, int n) {
  return q < 0 ? -q : (q >= n ? 2 * n - 2 - q : q);
}
__device__ __forceinline__ float lrelu(float v) { return v >= 0.f ? v : SLOPE * v; }
__device__ __forceinline__ unsigned short f2bf(float f) {
  unsigned int u = __float_as_uint(f);
  u += 0x7fffu + ((u >> 16) & 1u);
  return (unsigned short)(u >> 16);
}
__device__ __forceinline__ float bf2f(unsigned short h) {
  return __uint_as_float(((unsigned int)h) << 16);
}
__device__ __forceinline__ void gload_lds16(const void* g, void* l) {
  __builtin_amdgcn_global_load_lds(
      (const __attribute__((address_space(1))) unsigned int*)g,
      (__attribute__((address_space(3))) unsigned int*)l, 16, 0, 0);
}

// ---------------- kernel_predict: spatial weights ----------------
__global__ __launch_bounds__(256) void k_ws(const float* __restrict__ s,
                                            const float* __restrict__ sw,
                                            const float* __restrict__ sb,
                                            float* __restrict__ ws_out) {
  int bo = blockIdx.x;
  int o = bo & (CDIM - 1);
  int c = threadIdx.x;
  int b = bo >> 8;
  float sv[9], wv[9];
  const float* sp = s + (size_t)(b * CDIM + c) * 9;
  const float* wp = sw + (size_t)(o * CDIM + c) * 9;
#pragma unroll
  for (int i = 0; i < 9; i++) { sv[i] = sp[i]; wv[i] = wp[i]; }
  float out9[9];
#pragma unroll
  for (int i = 0; i < 3; i++)
#pragma unroll
    for (int j = 0; j < 3; j++) {
      float a = 0.f;
#pragma unroll
      for (int dy = 0; dy < 3; dy++) {
        int u = i + dy - 1; u = (u < 0) ? 1 : (u > 2 ? 1 : u);
#pragma unroll
        for (int dx = 0; dx < 3; dx++) {
          int v = j + dx - 1; v = (v < 0) ? 1 : (v > 2 ? 1 : v);
          a += sv[u * 3 + v] * wv[dy * 3 + dx];
        }
      }
      out9[i * 3 + j] = a;
    }
  __shared__ float red[256 * 9];
#pragma unroll
  for (int i = 0; i < 9; i++) red[c * 9 + i] = out9[i];
  __syncthreads();
  for (int st = 128; st > 0; st >>= 1) {
    if (c < st)
#pragma unroll
      for (int i = 0; i < 9; i++) red[c * 9 + i] += red[(c + st) * 9 + i];
    __syncthreads();
  }
  if (c < 9) ws_out[(size_t)bo * 9 + c] = red[c] + sb[o];
}

// ---------------- pooled + w_point / bias (fused) ----------------
__global__ __launch_bounds__(256) void k_point(const float* __restrict__ s,
                                               const float* __restrict__ pw,
                                               const float* __restrict__ pb,
                                               const float* __restrict__ bw,
                                               const float* __restrict__ bb,
                                               float* __restrict__ wp_out,
                                               float* __restrict__ bs_out) {
  int b = blockIdx.x, o = threadIdx.x;
  __shared__ float pl[CDIM];
  const float* sp = s + (size_t)(b * CDIM + o) * 9;
  float a9 = 0.f;
#pragma unroll
  for (int j = 0; j < 9; j++) a9 += sp[j];
  pl[o] = a9 * (1.f / 9.f);
  __syncthreads();
  float a = pb[o], d = bb[o];
  for (int c = 0; c < CDIM; c++) {
    float p = pl[c];
    a += p * pw[o * CDIM + c];
    d += p * bw[o * CDIM + c];
  }
  wp_out[b * CDIM + o] = a;
  bs_out[b * CDIM + o] = d;
}

__global__ __launch_bounds__(256) void k_istats(const float* __restrict__ x,
                                                float* __restrict__ mean,
                                                float* __restrict__ rstd, int HW) {
  int plane = blockIdx.x;
  const float4* p = (const float4*)(x + (size_t)plane * HW);
  int n4 = HW >> 2;
  float s = 0.f, q = 0.f;
  for (int i = threadIdx.x; i < n4; i += 256) {
    float4 v = p[i];
    s += v.x + v.y + v.z + v.w;
    q += v.x * v.x + v.y * v.y + v.z * v.z + v.w * v.w;
  }
  __shared__ float rs[256], rq[256];
  rs[threadIdx.x] = s; rq[threadIdx.x] = q;
  __syncthreads();
  for (int st = 128; st > 0; st >>= 1) {
    if (threadIdx.x < st) {
      rs[threadIdx.x] += rs[threadIdx.x + st];
      rq[threadIdx.x] += rq[threadIdx.x + st];
    }
    __syncthreads();
  }
  if (threadIdx.x == 0) {
    float m = rs[0] / HW;
    float v = rq[0] / HW - m * m;
    mean[plane] = m;
    rstd[plane] = rsqrtf(v + EPS);
  }
}

// ---------------- weight pack: OIHW f32 -> [tap][icc][mf][lane][8] bf16 (6 mats) ----------------
__global__ void k_packw6(const float* __restrict__ w0, const float* __restrict__ w1,
                         const float* __restrict__ w2, const float* __restrict__ w3,
                         const float* __restrict__ w4, const float* __restrict__ w5,
                         unsigned short* __restrict__ pk) {
  const float* ws[6] = {w0, w1, w2, w3, w4, w5};
  int seg = blockIdx.y;
  const float* w = ws[seg];
  int i = blockIdx.x * 256 + threadIdx.x;   // < 589824
  int j = i & 7, l = (i >> 3) & 63, mf = (i >> 9) & 15, icc = (i >> 13) & 7, tap = i >> 16;
  int oc = mf * 16 + (l & 15);
  int ic = icc * 32 + (l >> 4) * 8 + j;
  pk[(size_t)seg * PK_SZ + i] = f2bf(w[((size_t)oc * 256 + ic) * 9 + tap]);
}

// ---------------- fused IN + dynamic depthwise + pointwise -> NHWC bf16 ----------------
template <int LW>
__global__ __launch_bounds__(256) void k_dwt(const float* __restrict__ x,
                                             const float* __restrict__ ws,
                                             const float* __restrict__ mean,
                                             const float* __restrict__ rstd,
                                             const float* __restrict__ wp,
                                             const float* __restrict__ bs,
                                             unsigned short* __restrict__ out) {
  constexpr int W = 1 << LW, H = W, HW = W * W;
  int t = threadIdx.x;
  int xt = (LW > 6) ? (blockIdx.x & ((W >> 6) - 1)) : 0;
  int icb = (LW > 6) ? (blockIdx.x >> (LW - 6)) : blockIdx.x;
  int y = blockIdx.y, b = blockIdx.z;
  __shared__ unsigned short tr[64][66];
  int xl = t & 63;
  int xx = xt * 64 + xl;
  int sy0 = refl(y - 1, H), sy1 = y, sy2 = refl(y + 1, H);
  int sx0 = refl(xx - 1, W), sx2 = refl(xx + 1, W);
#pragma unroll
  for (int rr = 0; rr < 16; ++rr) {
    int icl = rr * 4 + (t >> 6);
    int plane = b * CDIM + icb * 64 + icl;
    const float* xp = x + (size_t)plane * HW;
    float m = mean[plane], r = rstd[plane], sc = wp[plane], bi = bs[plane];
    const float* w9 = ws + (size_t)plane * 9;
    float a = w9[0] * (xp[sy0 * W + sx0] - m) + w9[1] * (xp[sy0 * W + xx] - m) +
              w9[2] * (xp[sy0 * W + sx2] - m) + w9[3] * (xp[sy1 * W + sx0] - m) +
              w9[4] * (xp[sy1 * W + xx] - m) + w9[5] * (xp[sy1 * W + sx2] - m) +
              w9[6] * (xp[sy2 * W + sx0] - m) + w9[7] * (xp[sy2 * W + xx] - m) +
              w9[8] * (xp[sy2 * W + sx2] - m);
    tr[icl][xl] = f2bf(a * r * sc + bi);
  }
  __syncthreads();
#pragma unroll
  for (int rr = 0; rr < 16; ++rr) {
    int xl2 = rr * 4 + (t >> 6);
    int icl2 = t & 63;
    out[((size_t)((b * H + y) * W + xt * 64 + xl2)) * CDIM + icb * 64 + icl2] = tr[icl2][xl2];
  }
}

// ---------------- 2x2 avg pool on NHWC bf16 ----------------
__global__ __launch_bounds__(256) void k_pool_nhwc(const unsigned short* __restrict__ in,
                                                   unsigned short* __restrict__ out) {
  int t = threadIdx.x;
  int p = blockIdx.x;                 // (b*64+Y)*64+X
  int X = p & 63, Y = (p >> 6) & 63, b = p >> 12;
  const unsigned short* s = in + (((size_t)(b * 128 + 2 * Y) * 128 + 2 * X) * CDIM + t);
  float a = bf2f(s[0]) + bf2f(s[CDIM]) + bf2f(s[128 * CDIM]) + bf2f(s[128 * CDIM + CDIM]);
  out[(size_t)p * CDIM + t] = f2bf(0.25f * a);
}

// ---------------- MFMA implicit-GEMM 3x3 reflect conv, counted-vmcnt pipeline ----------------
// block 256 (4 waves), tile 64 oc x 256 pixels. Full LDS double-buffer (tin+w),
// raw s_barrier + counted s_waitcnt vmcnt(STN): next stage stays in flight
// across the barriers; no vmcnt(0) drain in the main loop. 1 block/CU.
template <int LW, bool DUAL, bool UPSB, bool NCHWOUT>
__global__ __launch_bounds__(256) void k_conv_mfma(
    const unsigned short* __restrict__ srcA, const unsigned short* __restrict__ srcB,
    const unsigned short* __restrict__ wpkA, const unsigned short* __restrict__ wpkB,
    const float* __restrict__ bias, void* __restrict__ outp) {
  constexpr int W = 1 << LW, H = W, HW = W * W;
  constexpr int ROWS = 256 >> LW;       // pixel rows per block
  constexpr int R = ROWS + 2, Cw = W + 2;
  constexpr int RC = R * Cw;
  constexpr int RCPAD = (RC + 63) & ~63;
  constexpr int NIT = RCPAD / 64;
  constexpr int STN = NIT + 9;          // gload_lds instrs per stage (exact vmcnt unit)
  __shared__ __align__(16) unsigned short tin[2][RCPAD * 32];
  __shared__ __align__(16) unsigned short wlds[2][9 * 256 * 8];

  const int t = threadIdx.x;
  const int l = t & 63, wv = t >> 6;
  const int l15 = l & 15, l4 = l >> 4;
  const int mb = blockIdx.x;
  const int pixbase = blockIdx.y * 256;
  const int b = pixbase >> (2 * LW);
  const int y0 = (pixbase >> LW) & (H - 1);

  f32x4 acc[4][4];
#pragma unroll
  for (int mi = 0; mi < 4; mi++)
#pragma unroll
    for (int nf = 0; nf < 4; nf++) acc[mi][nf] = (f32x4){0.f, 0.f, 0.f, 0.f};

  // precompute per-lane staging pointers for both sources
  const unsigned short* inA[NIT];
  const unsigned short* inB[NIT];
#pragma unroll
  for (int it = 0; it < NIT; ++it) {
    int rc = it * 64 + (t >> 2);
    int rcc = rc < RC - 1 ? rc : RC - 1;
    int r = rcc / Cw, tc = rcc - r * Cw;
    int gy = refl(y0 - 1 + r, H);
    int gx = refl(tc - 1, W);
    int gsrc = (t & 3) ^ (tc & 3);      // ic-slot XOR swizzle (source side)
    inA[it] = srcA + (((size_t)(b * W + gy) * W + gx) * CDIM + gsrc * 8);
    if (DUAL) {
      int sy, sx, sw;
      if (UPSB) { sy = gy >> 1; sx = gx >> 1; sw = W >> 1; }
      else      { sy = gy;      sx = gx;      sw = W; }
      inB[it] = srcB + (((size_t)(b * sw + sy) * sw + sx) * CDIM + gsrc * 8);
    } else {
      inB[it] = nullptr;
    }
  }
  const unsigned short* wsA = wpkA + ((size_t)(mb * 4 + wv) * 64 + l) * 8;
  const unsigned short* wsB = DUAL ? wpkB + ((size_t)(mb * 4 + wv) * 64 + l) * 8 : nullptr;

  const int NK = DUAL ? 16 : 8;

  auto STAGE = [&](int kk, int bsel) {
    const int icc = kk & 7;
    const bool useB = DUAL && (kk >= 8);
#pragma unroll
    for (int it = 0; it < NIT; ++it) {
      const unsigned short* p = useB ? inB[it] : inA[it];
      gload_lds16(p + icc * 32, &tin[bsel][(size_t)(it * 256 + t) * 8]);
    }
    const unsigned short* ws = useB ? wsB : wsA;
#pragma unroll
    for (int tap = 0; tap < 9; ++tap)
      gload_lds16(ws + ((size_t)tap * 8 + icc) * 8192,
                  &wlds[bsel][(size_t)(tap * 256 + t) * 8]);
  };

  STAGE(0, 0);
#pragma unroll 1
  for (int kk = 0; kk < NK; ++kk) {
    if (kk + 1 < NK) {
      STAGE(kk + 1, (kk + 1) & 1);
      asm volatile("s_waitcnt vmcnt(%0)" ::"n"(STN) : "memory");  // drain prev stage only
    } else {
      asm volatile("s_waitcnt vmcnt(0)" ::: "memory");
    }
    __builtin_amdgcn_s_barrier();

    const int sel = kk & 1;
#pragma unroll
    for (int tap = 0; tap < 9; ++tap) {
      const int dy = tap / 3, dx = tap - 3 * (tap / 3);
      bf16x8 af[4];
#pragma unroll
      for (int mi = 0; mi < 4; mi++)
        af[mi] = *(const bf16x8*)&wlds[sel][(size_t)((tap * 4 + mi) * 64 + l) * 8];
#pragma unroll
      for (int nf = 0; nf < 4; nf++) {
        int pl = wv * 64 + nf * 16 + l15;
        int py = pl >> LW;
        int c = pl & (W - 1);
        int tcol = c + dx;
        int idx16 = ((py + dy) * Cw + tcol) * 4 + (l4 ^ (tcol & 3));
        bf16x8 bfv = *(const bf16x8*)&tin[sel][(size_t)idx16 * 8];
#pragma unroll
        for (int mi = 0; mi < 4; mi++)
          acc[mi][nf] = __builtin_amdgcn_mfma_f32_16x16x32_bf16(af[mi], bfv, acc[mi][nf], 0, 0, 0);
      }
    }
    if (kk + 1 < NK) __builtin_amdgcn_s_barrier();   // all waves done reading buf before overwrite
  }

  // epilogue
#pragma unroll
  for (int mi = 0; mi < 4; mi++) {
    int oc0 = mb * 64 + mi * 16 + l4 * 4;
    float bv[4];
#pragma unroll
    for (int rr = 0; rr < 4; rr++) bv[rr] = bias ? bias[oc0 + rr] : 0.f;
#pragma unroll
    for (int nf = 0; nf < 4; nf++) {
      int p = pixbase + wv * 64 + nf * 16 + l15;
      if (NCHWOUT) {
        float* o = (float*)outp;
        int pin = p & (HW - 1);
        int bb2 = p >> (2 * LW);
#pragma unroll
        for (int rr = 0; rr < 4; rr++)
          o[((size_t)(bb2 * CDIM + oc0 + rr)) * HW + pin] = lrelu(acc[mi][nf][rr] + bv[rr]);
      } else {
        unsigned short* o = (unsigned short*)outp;
        ushort4 pk;
        pk.x = f2bf(lrelu(acc[mi][nf][0] + bv[0]));
        pk.y = f2bf(lrelu(acc[mi][nf][1] + bv[1]));
        pk.z = f2bf(lrelu(acc[mi][nf][2] + bv[2]));
        pk.w = f2bf(lrelu(acc[mi][nf][3] + bv[3]));
        *(ushort4*)&o[(size_t)p * CDIM + oc0] = pk;
      }
    }
  }
}

// ---------------- host ----------------
extern "C" void kernel_launch(void* const* d_in, const int* in_sizes, int n_in,
                              void* d_out, int out_size, void* d_ws, size_t ws_size,
                              hipStream_t stream) {
  (void)in_sizes; (void)n_in; (void)out_size;
  const float* c_hf = (const float*)d_in[0];
  const float* c_lf = (const float*)d_in[1];
  const float* s_hf = (const float*)d_in[2];
  const float* s_lf = (const float*)d_in[3];
  const float* h_sw = (const float*)d_in[4];
  const float* h_sb = (const float*)d_in[5];
  const float* h_pw = (const float*)d_in[6];
  const float* h_pb = (const float*)d_in[7];
  const float* h_bw = (const float*)d_in[8];
  const float* h_bb = (const float*)d_in[9];
  const float* l_sw = (const float*)d_in[10];
  const float* l_sb = (const float*)d_in[11];
  const float* l_pw = (const float*)d_in[12];
  const float* l_pb = (const float*)d_in[13];
  const float* l_bw = (const float*)d_in[14];
  const float* l_bb = (const float*)d_in[15];
  const float* ada_h_w = (const float*)d_in[16];
  const float* ada_h_b = (const float*)d_in[17];
  const float* ada_l_w = (const float*)d_in[18];
  const float* ada_l_b = (const float*)d_in[19];
  const float* h2h = (const float*)d_in[20];
  const float* l2h = (const float*)d_in[21];
  const float* h2l = (const float*)d_in[22];
  const float* l2l = (const float*)d_in[23];

  const int B = 4, H = 128, W = 128;

  float* base;
  size_t need = (size_t)TOTAL_F * sizeof(float);
  if (ws_size >= need) {
    base = (float*)d_ws;
  } else {
    void* p = nullptr;
    hipGetSymbolAddress(&p, HIP_SYMBOL(g_scratch));
    base = (float*)p;
  }

  float* ws_hf = base + OFF_WS_HF;
  float* ws_lf = base + OFF_WS_LF;
  float* wp_hf = base + OFF_WP_HF;
  float* bs_hf = base + OFF_BS_HF;
  float* wp_lf = base + OFF_WP_LF;
  float* bs_lf = base + OFF_BS_LF;
  float* mean_hf = base + OFF_MEAN_HF;
  float* rstd_hf = base + OFF_RSTD_HF;
  float* mean_lf = base + OFF_MEAN_LF;
  float* rstd_lf = base + OFF_RSTD_LF;
  unsigned short* u16 = (unsigned short*)(base + OFF_U16);
  unsigned short* yh = u16 + U_YH;
  unsigned short* yl = u16 + U_YL;
  unsigned short* hfA = u16 + U_HFA;
  unsigned short* lfA = u16 + U_LFA;
  unsigned short* hfP = u16 + U_HFP;
  unsigned short* pk      = u16 + U_PK;
  unsigned short* pk_adah = pk + 0 * PK_SZ;
  unsigned short* pk_h2h  = pk + 1 * PK_SZ;
  unsigned short* pk_l2h  = pk + 2 * PK_SZ;
  unsigned short* pk_adal = pk + 3 * PK_SZ;
  unsigned short* pk_l2l  = pk + 4 * PK_SZ;
  unsigned short* pk_h2l  = pk + 5 * PK_SZ;

  float* out_hf = (float*)d_out;
  float* out_lf = (float*)d_out + 16777216;

  // weight packing (6 matrices in one launch)
  k_packw6<<<dim3(2304, 6), dim3(256), 0, stream>>>(ada_h_w, h2h, l2h, ada_l_w, l2l, h2l, pk);

  // kernel_predict
  k_ws<<<dim3(B * CDIM), dim3(256), 0, stream>>>(s_hf, h_sw, h_sb, ws_hf);
  k_ws<<<dim3(B * CDIM), dim3(256), 0, stream>>>(s_lf, l_sw, l_sb, ws_lf);
  k_point<<<dim3(B), dim3(256), 0, stream>>>(s_hf, h_pw, h_pb, h_bw, h_bb, wp_hf, bs_hf);
  k_point<<<dim3(B), dim3(256), 0, stream>>>(s_lf, l_pw, l_pb, l_bw, l_bb, wp_lf, bs_lf);

  // instance norm stats
  k_istats<<<dim3(B * CDIM), dim3(256), 0, stream>>>(c_hf, mean_hf, rstd_hf, H * W);
  k_istats<<<dim3(B * CDIM), dim3(256), 0, stream>>>(c_lf, mean_lf, rstd_lf, (H / 2) * (W / 2));

  // fused IN + depthwise + pointwise -> NHWC bf16
  k_dwt<7><<<dim3(8, 128, 4), dim3(256), 0, stream>>>(c_hf, ws_hf, mean_hf, rstd_hf, wp_hf, bs_hf, yh);
  k_dwt<6><<<dim3(4, 64, 4), dim3(256), 0, stream>>>(c_lf, ws_lf, mean_lf, rstd_lf, wp_lf, bs_lf, yl);

  // ada convs (MFMA), bf16 NHWC out, lrelu
  k_conv_mfma<7, false, false, false><<<dim3(4, 256), dim3(256), 0, stream>>>(
      yh, nullptr, pk_adah, nullptr, ada_h_b, hfA);
  k_conv_mfma<6, false, false, false><<<dim3(4, 64), dim3(256), 0, stream>>>(
      yl, nullptr, pk_adal, nullptr, ada_l_b, lfA);

  // avgpool hf
  k_pool_nhwc<<<dim3(16384), dim3(256), 0, stream>>>(hfA, hfP);

  // fused output convs (MFMA), f32 NCHW out, lrelu
  k_conv_mfma<7, true, true, true><<<dim3(4, 256), dim3(256), 0, stream>>>(
      hfA, lfA, pk_h2h, pk_l2h, nullptr, out_hf);
  k_conv_mfma<6, true, false, true><<<dim3(4, 64), dim3(256), 0, stream>>>(
      lfA, hfP, pk_l2l, pk_h2l, nullptr, out_lf);
}

// Round 5
// 479.402 us; speedup vs baseline: 1.1913x; 1.1913x over previous
//
#include <hip/hip_runtime.h>
#include <hip/hip_bf16.h>

#define CDIM 256
#define EPS 1e-5f
#define SLOPE 0.01f

using f32x4  = __attribute__((ext_vector_type(4))) float;
typedef __bf16 bf16x8 __attribute__((ext_vector_type(8)));
typedef unsigned short u16x8 __attribute__((ext_vector_type(8)));

// ---------------- workspace layout ----------------
enum : size_t {
  OFF_WS_HF   = 0,
  OFF_WS_LF   = 9216,
  OFF_WP_HF   = 20480,
  OFF_BS_HF   = 21504,
  OFF_WP_LF   = 22528,
  OFF_BS_LF   = 23552,
  OFF_MEAN_HF = 24576,
  OFF_RSTD_HF = 25600,
  OFF_MEAN_LF = 26624,
  OFF_RSTD_LF = 27648,
  OFF_U16     = 32768,          // start of ushort region (float units)
};
// ushort offsets relative to u16 base
enum : size_t {
  U_YH  = 0,          // [4][128][128][256] bf16
  U_YL  = 16777216,   // [4][64][64][256]
  U_HFA = 20971520,   // [4][128][128][256]
  U_LFA = 37748736,   // [4][64][64][256]
  U_HFP = 41943040,   // [4][64][64][256]
  U_PK  = 46137344,   // 6 packed weights, each 589824
  PK_SZ = 589824,
  U_END = U_PK + 6 * PK_SZ,
};
enum : size_t { TOTAL_F = OFF_U16 + (U_END + 1) / 2 };

__device__ float g_scratch[TOTAL_F];

__device__ __forceinline__ int refl(int q, int n) {
  return q < 0 ? -q : (q >= n ? 2 * n - 2 - q : q);
}
__device__ __forceinline__ float lrelu(float v) { return v >= 0.f ? v : SLOPE * v; }
__device__ __forceinline__ unsigned short f2bf(float f) {
  unsigned int u = __float_as_uint(f);
  u += 0x7fffu + ((u >> 16) & 1u);
  return (unsigned short)(u >> 16);
}
__device__ __forceinline__ float bf2f(unsigned short h) {
  return __uint_as_float(((unsigned int)h) << 16);
}
__device__ __forceinline__ void gload_lds16(const void* g, void* l) {
  __builtin_amdgcn_global_load_lds(
      (const __attribute__((address_space(1))) unsigned int*)g,
      (__attribute__((address_space(3))) unsigned int*)l, 16, 0, 0);
}

// ---------------- kernel_predict: spatial weights ----------------
__global__ __launch_bounds__(256) void k_ws(const float* __restrict__ s,
                                            const float* __restrict__ sw,
                                            const float* __restrict__ sb,
                                            float* __restrict__ ws_out) {
  int bo = blockIdx.x;
  int o = bo & (CDIM - 1);
  int c = threadIdx.x;
  int b = bo >> 8;
  float sv[9], wv[9];
  const float* sp = s + (size_t)(b * CDIM + c) * 9;
  const float* wp = sw + (size_t)(o * CDIM + c) * 9;
#pragma unroll
  for (int i = 0; i < 9; i++) { sv[i] = sp[i]; wv[i] = wp[i]; }
  float out9[9];
#pragma unroll
  for (int i = 0; i < 3; i++)
#pragma unroll
    for (int j = 0; j < 3; j++) {
      float a = 0.f;
#pragma unroll
      for (int dy = 0; dy < 3; dy++) {
        int u = i + dy - 1; u = (u < 0) ? 1 : (u > 2 ? 1 : u);
#pragma unroll
        for (int dx = 0; dx < 3; dx++) {
          int v = j + dx - 1; v = (v < 0) ? 1 : (v > 2 ? 1 : v);
          a += sv[u * 3 + v] * wv[dy * 3 + dx];
        }
      }
      out9[i * 3 + j] = a;
    }
  __shared__ float red[256 * 9];
#pragma unroll
  for (int i = 0; i < 9; i++) red[c * 9 + i] = out9[i];
  __syncthreads();
  for (int st = 128; st > 0; st >>= 1) {
    if (c < st)
#pragma unroll
      for (int i = 0; i < 9; i++) red[c * 9 + i] += red[(c + st) * 9 + i];
    __syncthreads();
  }
  if (c < 9) ws_out[(size_t)bo * 9 + c] = red[c] + sb[o];
}

// ---------------- pooled + w_point / bias (fused) ----------------
__global__ __launch_bounds__(256) void k_point(const float* __restrict__ s,
                                               const float* __restrict__ pw,
                                               const float* __restrict__ pb,
                                               const float* __restrict__ bw,
                                               const float* __restrict__ bb,
                                               float* __restrict__ wp_out,
                                               float* __restrict__ bs_out) {
  int b = blockIdx.x, o = threadIdx.x;
  __shared__ float pl[CDIM];
  const float* sp = s + (size_t)(b * CDIM + o) * 9;
  float a9 = 0.f;
#pragma unroll
  for (int j = 0; j < 9; j++) a9 += sp[j];
  pl[o] = a9 * (1.f / 9.f);
  __syncthreads();
  float a = pb[o], d = bb[o];
  for (int c = 0; c < CDIM; c++) {
    float p = pl[c];
    a += p * pw[o * CDIM + c];
    d += p * bw[o * CDIM + c];
  }
  wp_out[b * CDIM + o] = a;
  bs_out[b * CDIM + o] = d;
}

__global__ __launch_bounds__(256) void k_istats(const float* __restrict__ x,
                                                float* __restrict__ mean,
                                                float* __restrict__ rstd, int HW) {
  int plane = blockIdx.x;
  const float4* p = (const float4*)(x + (size_t)plane * HW);
  int n4 = HW >> 2;
  float s = 0.f, q = 0.f;
  for (int i = threadIdx.x; i < n4; i += 256) {
    float4 v = p[i];
    s += v.x + v.y + v.z + v.w;
    q += v.x * v.x + v.y * v.y + v.z * v.z + v.w * v.w;
  }
  __shared__ float rs[256], rq[256];
  rs[threadIdx.x] = s; rq[threadIdx.x] = q;
  __syncthreads();
  for (int st = 128; st > 0; st >>= 1) {
    if (threadIdx.x < st) {
      rs[threadIdx.x] += rs[threadIdx.x + st];
      rq[threadIdx.x] += rq[threadIdx.x + st];
    }
    __syncthreads();
  }
  if (threadIdx.x == 0) {
    float m = rs[0] / HW;
    float v = rq[0] / HW - m * m;
    mean[plane] = m;
    rstd[plane] = rsqrtf(v + EPS);
  }
}

// ---------------- weight pack: OIHW f32 -> [tap][icc][mf][lane][8] bf16 (6 mats) ----------------
__global__ void k_packw6(const float* __restrict__ w0, const float* __restrict__ w1,
                         const float* __restrict__ w2, const float* __restrict__ w3,
                         const float* __restrict__ w4, const float* __restrict__ w5,
                         unsigned short* __restrict__ pk) {
  const float* ws[6] = {w0, w1, w2, w3, w4, w5};
  int seg = blockIdx.y;
  const float* w = ws[seg];
  int i = blockIdx.x * 256 + threadIdx.x;   // < 589824
  int j = i & 7, l = (i >> 3) & 63, mf = (i >> 9) & 15, icc = (i >> 13) & 7, tap = i >> 16;
  int oc = mf * 16 + (l & 15);
  int ic = icc * 32 + (l >> 4) * 8 + j;
  pk[(size_t)seg * PK_SZ + i] = f2bf(w[((size_t)oc * 256 + ic) * 9 + tap]);
}

// ---------------- fused IN + dynamic depthwise + pointwise -> NHWC bf16 ----------------
template <int LW>
__global__ __launch_bounds__(256) void k_dwt(const float* __restrict__ x,
                                             const float* __restrict__ ws,
                                             const float* __restrict__ mean,
                                             const float* __restrict__ rstd,
                                             const float* __restrict__ wp,
                                             const float* __restrict__ bs,
                                             unsigned short* __restrict__ out) {
  constexpr int W = 1 << LW, H = W, HW = W * W;
  int t = threadIdx.x;
  int xt = (LW > 6) ? (blockIdx.x & ((W >> 6) - 1)) : 0;
  int icb = (LW > 6) ? (blockIdx.x >> (LW - 6)) : blockIdx.x;
  int y = blockIdx.y, b = blockIdx.z;
  __shared__ unsigned short tr[64][66];
  int xl = t & 63;
  int xx = xt * 64 + xl;
  int sy0 = refl(y - 1, H), sy1 = y, sy2 = refl(y + 1, H);
  int sx0 = refl(xx - 1, W), sx2 = refl(xx + 1, W);
#pragma unroll
  for (int rr = 0; rr < 16; ++rr) {
    int icl = rr * 4 + (t >> 6);
    int plane = b * CDIM + icb * 64 + icl;
    const float* xp = x + (size_t)plane * HW;
    float m = mean[plane], r = rstd[plane], sc = wp[plane], bi = bs[plane];
    const float* w9 = ws + (size_t)plane * 9;
    float a = w9[0] * (xp[sy0 * W + sx0] - m) + w9[1] * (xp[sy0 * W + xx] - m) +
              w9[2] * (xp[sy0 * W + sx2] - m) + w9[3] * (xp[sy1 * W + sx0] - m) +
              w9[4] * (xp[sy1 * W + xx] - m) + w9[5] * (xp[sy1 * W + sx2] - m) +
              w9[6] * (xp[sy2 * W + sx0] - m) + w9[7] * (xp[sy2 * W + xx] - m) +
              w9[8] * (xp[sy2 * W + sx2] - m);
    tr[icl][xl] = f2bf(a * r * sc + bi);
  }
  __syncthreads();
#pragma unroll
  for (int rr = 0; rr < 16; ++rr) {
    int xl2 = rr * 4 + (t >> 6);
    int icl2 = t & 63;
    out[((size_t)((b * H + y) * W + xt * 64 + xl2)) * CDIM + icb * 64 + icl2] = tr[icl2][xl2];
  }
}

// ---------------- 2x2 avg pool on NHWC bf16 (vectorized: 8 ch / thread) ----------------
__global__ __launch_bounds__(256) void k_pool_nhwc(const unsigned short* __restrict__ in,
                                                   unsigned short* __restrict__ out) {
  int i = blockIdx.x * 256 + threadIdx.x;   // < 4*64*64*32
  int cg = i & 31;
  int p = i >> 5;                            // (b*64+Y)*64+X
  int X = p & 63, Y = (p >> 6) & 63, b = p >> 12;
  const unsigned short* s =
      in + ((size_t)(b * 128 + 2 * Y) * 128 + 2 * X) * CDIM + cg * 8;
  u16x8 v0 = *(const u16x8*)(s);
  u16x8 v1 = *(const u16x8*)(s + CDIM);
  u16x8 v2 = *(const u16x8*)(s + 128 * CDIM);
  u16x8 v3 = *(const u16x8*)(s + 128 * CDIM + CDIM);
  u16x8 r;
#pragma unroll
  for (int j = 0; j < 8; j++)
    r[j] = f2bf(0.25f * (bf2f(v0[j]) + bf2f(v1[j]) + bf2f(v2[j]) + bf2f(v3[j])));
  *(u16x8*)(out + (size_t)p * CDIM + cg * 8) = r;
}

// ---------------- MFMA implicit-GEMM 3x3 reflect conv ----------------
// block 256 (4 waves), tile 64 oc x 256 pixels. Single-buffer, 2 barriers per
// icc-step (R3 structure; 2 blocks/CU overlap). 1D grid with XCD-chunked
// bijective swizzle: all 4 oc-groups of a pixel tile + consecutive tiles land
// on one XCD -> input/weights stay L2-hot. setprio(1) around MFMA cluster.
template <int LW, bool DUAL, bool UPSB, bool NCHWOUT>
__global__ __launch_bounds__(256, 2) void k_conv_mfma(
    const unsigned short* __restrict__ srcA, const unsigned short* __restrict__ srcB,
    const unsigned short* __restrict__ wpkA, const unsigned short* __restrict__ wpkB,
    const float* __restrict__ bias, void* __restrict__ outp) {
  constexpr int W = 1 << LW, H = W, HW = W * W;
  constexpr int ROWS = 256 >> LW;       // pixel rows per block
  constexpr int R = ROWS + 2, Cw = W + 2;
  constexpr int RC = R * Cw;
  constexpr int RCPAD = (RC + 63) & ~63;
  constexpr int NIT = RCPAD / 64;
  __shared__ __align__(16) unsigned short tin[RCPAD * 32];        // input tile, 32 ic
  __shared__ __align__(16) unsigned short wlds[9 * 4 * 64 * 8];   // 9 taps x 4 mi frags

  const int t = threadIdx.x;
  const int l = t & 63, wv = t >> 6;
  const int l15 = l & 15, l4 = l >> 4;

  // XCD-chunked bijective swizzle (nwg divisible by 8)
  const int hwid = blockIdx.x;
  const int nwg = gridDim.x;
  const int wk = (hwid & 7) * (nwg >> 3) + (hwid >> 3);
  const int mb = wk & 3;
  const int pixbase = (wk >> 2) * 256;
  const int b = pixbase >> (2 * LW);
  const int y0 = (pixbase >> LW) & (H - 1);

  f32x4 acc[4][4];
#pragma unroll
  for (int mi = 0; mi < 4; mi++)
#pragma unroll
    for (int nf = 0; nf < 4; nf++) acc[mi][nf] = (f32x4){0.f, 0.f, 0.f, 0.f};

  const int nsrc = DUAL ? 2 : 1;
  for (int src = 0; src < nsrc; ++src) {
    const unsigned short* ysrc = src ? srcB : srcA;
    const unsigned short* wpk = src ? wpkB : wpkA;
    const bool ups = UPSB && (src == 1);

    // hoist staging addresses out of the K loop
    const unsigned short* inptr[NIT];
#pragma unroll
    for (int it = 0; it < NIT; ++it) {
      int rc = it * 64 + (t >> 2);
      int rcc = rc < RC - 1 ? rc : RC - 1;
      int r = rcc / Cw, tc = rcc - r * Cw;
      int gy = refl(y0 - 1 + r, H);
      int gx = refl(tc - 1, W);
      int sy, sx, sw;
      if (ups) { sy = gy >> 1; sx = gx >> 1; sw = W >> 1; }
      else     { sy = gy;      sx = gx;      sw = W; }
      int gsrc = (t & 3) ^ (tc & 3);   // ic-slot XOR swizzle (source side)
      inptr[it] = ysrc + (((size_t)(b * sw + sy) * sw + sx) * CDIM + gsrc * 8);
    }
    const unsigned short* wsrc = wpk + ((size_t)(mb * 4 + wv) * 64 + l) * 8;

    for (int icc = 0; icc < 8; ++icc) {
      __syncthreads();
#pragma unroll
      for (int it = 0; it < NIT; ++it)
        gload_lds16(inptr[it] + icc * 32, &tin[(size_t)(it * 256 + t) * 8]);
#pragma unroll
      for (int tap = 0; tap < 9; ++tap)
        gload_lds16(wsrc + ((size_t)tap * 8 + (size_t)icc) * 8192,
                    &wlds[(size_t)(tap * 256 + t) * 8]);
      __syncthreads();

      __builtin_amdgcn_s_setprio(1);
#pragma unroll
      for (int tap = 0; tap < 9; ++tap) {
        const int dy = tap / 3, dx = tap - 3 * (tap / 3);
        bf16x8 af[4];
#pragma unroll
        for (int mi = 0; mi < 4; mi++)
          af[mi] = *(const bf16x8*)&wlds[(size_t)((tap * 4 + mi) * 64 + l) * 8];
#pragma unroll
        for (int nf = 0; nf < 4; nf++) {
          int pl = wv * 64 + nf * 16 + l15;
          int py = pl >> LW;
          int c = pl & (W - 1);
          int tcol = c + dx;
          int idx16 = ((py + dy) * Cw + tcol) * 4 + (l4 ^ (tcol & 3));
          bf16x8 bfv = *(const bf16x8*)&tin[(size_t)idx16 * 8];
#pragma unroll
          for (int mi = 0; mi < 4; mi++)
            acc[mi][nf] = __builtin_amdgcn_mfma_f32_16x16x32_bf16(af[mi], bfv, acc[mi][nf], 0, 0, 0);
        }
      }
      __builtin_amdgcn_s_setprio(0);
    }
  }

  // epilogue
#pragma unroll
  for (int mi = 0; mi < 4; mi++) {
    int oc0 = mb * 64 + mi * 16 + l4 * 4;
    float bv[4];
#pragma unroll
    for (int rr = 0; rr < 4; rr++) bv[rr] = bias ? bias[oc0 + rr] : 0.f;
#pragma unroll
    for (int nf = 0; nf < 4; nf++) {
      int p = pixbase + wv * 64 + nf * 16 + l15;
      if (NCHWOUT) {
        float* o = (float*)outp;
        int pin = p & (HW - 1);
        int bb2 = p >> (2 * LW);
#pragma unroll
        for (int rr = 0; rr < 4; rr++)
          o[((size_t)(bb2 * CDIM + oc0 + rr)) * HW + pin] = lrelu(acc[mi][nf][rr] + bv[rr]);
      } else {
        unsigned short* o = (unsigned short*)outp;
        ushort4 pk;
        pk.x = f2bf(lrelu(acc[mi][nf][0] + bv[0]));
        pk.y = f2bf(lrelu(acc[mi][nf][1] + bv[1]));
        pk.z = f2bf(lrelu(acc[mi][nf][2] + bv[2]));
        pk.w = f2bf(lrelu(acc[mi][nf][3] + bv[3]));
        *(ushort4*)&o[(size_t)p * CDIM + oc0] = pk;
      }
    }
  }
}

// ---------------- host ----------------
extern "C" void kernel_launch(void* const* d_in, const int* in_sizes, int n_in,
                              void* d_out, int out_size, void* d_ws, size_t ws_size,
                              hipStream_t stream) {
  (void)in_sizes; (void)n_in; (void)out_size;
  const float* c_hf = (const float*)d_in[0];
  const float* c_lf = (const float*)d_in[1];
  const float* s_hf = (const float*)d_in[2];
  const float* s_lf = (const float*)d_in[3];
  const float* h_sw = (const float*)d_in[4];
  const float* h_sb = (const float*)d_in[5];
  const float* h_pw = (const float*)d_in[6];
  const float* h_pb = (const float*)d_in[7];
  const float* h_bw = (const float*)d_in[8];
  const float* h_bb = (const float*)d_in[9];
  const float* l_sw = (const float*)d_in[10];
  const float* l_sb = (const float*)d_in[11];
  const float* l_pw = (const float*)d_in[12];
  const float* l_pb = (const float*)d_in[13];
  const float* l_bw = (const float*)d_in[14];
  const float* l_bb = (const float*)d_in[15];
  const float* ada_h_w = (const float*)d_in[16];
  const float* ada_h_b = (const float*)d_in[17];
  const float* ada_l_w = (const float*)d_in[18];
  const float* ada_l_b = (const float*)d_in[19];
  const float* h2h = (const float*)d_in[20];
  const float* l2h = (const float*)d_in[21];
  const float* h2l = (const float*)d_in[22];
  const float* l2l = (const float*)d_in[23];

  const int B = 4, H = 128, W = 128;

  float* base;
  size_t need = (size_t)TOTAL_F * sizeof(float);
  if (ws_size >= need) {
    base = (float*)d_ws;
  } else {
    void* p = nullptr;
    hipGetSymbolAddress(&p, HIP_SYMBOL(g_scratch));
    base = (float*)p;
  }

  float* ws_hf = base + OFF_WS_HF;
  float* ws_lf = base + OFF_WS_LF;
  float* wp_hf = base + OFF_WP_HF;
  float* bs_hf = base + OFF_BS_HF;
  float* wp_lf = base + OFF_WP_LF;
  float* bs_lf = base + OFF_BS_LF;
  float* mean_hf = base + OFF_MEAN_HF;
  float* rstd_hf = base + OFF_RSTD_HF;
  float* mean_lf = base + OFF_MEAN_LF;
  float* rstd_lf = base + OFF_RSTD_LF;
  unsigned short* u16 = (unsigned short*)(base + OFF_U16);
  unsigned short* yh = u16 + U_YH;
  unsigned short* yl = u16 + U_YL;
  unsigned short* hfA = u16 + U_HFA;
  unsigned short* lfA = u16 + U_LFA;
  unsigned short* hfP = u16 + U_HFP;
  unsigned short* pk      = u16 + U_PK;
  unsigned short* pk_adah = pk + 0 * PK_SZ;
  unsigned short* pk_h2h  = pk + 1 * PK_SZ;
  unsigned short* pk_l2h  = pk + 2 * PK_SZ;
  unsigned short* pk_adal = pk + 3 * PK_SZ;
  unsigned short* pk_l2l  = pk + 4 * PK_SZ;
  unsigned short* pk_h2l  = pk + 5 * PK_SZ;

  float* out_hf = (float*)d_out;
  float* out_lf = (float*)d_out + 16777216;

  // weight packing (6 matrices in one launch)
  k_packw6<<<dim3(2304, 6), dim3(256), 0, stream>>>(ada_h_w, h2h, l2h, ada_l_w, l2l, h2l, pk);

  // kernel_predict
  k_ws<<<dim3(B * CDIM), dim3(256), 0, stream>>>(s_hf, h_sw, h_sb, ws_hf);
  k_ws<<<dim3(B * CDIM), dim3(256), 0, stream>>>(s_lf, l_sw, l_sb, ws_lf);
  k_point<<<dim3(B), dim3(256), 0, stream>>>(s_hf, h_pw, h_pb, h_bw, h_bb, wp_hf, bs_hf);
  k_point<<<dim3(B), dim3(256), 0, stream>>>(s_lf, l_pw, l_pb, l_bw, l_bb, wp_lf, bs_lf);

  // instance norm stats
  k_istats<<<dim3(B * CDIM), dim3(256), 0, stream>>>(c_hf, mean_hf, rstd_hf, H * W);
  k_istats<<<dim3(B * CDIM), dim3(256), 0, stream>>>(c_lf, mean_lf, rstd_lf, (H / 2) * (W / 2));

  // fused IN + depthwise + pointwise -> NHWC bf16
  k_dwt<7><<<dim3(8, 128, 4), dim3(256), 0, stream>>>(c_hf, ws_hf, mean_hf, rstd_hf, wp_hf, bs_hf, yh);
  k_dwt<6><<<dim3(4, 64, 4), dim3(256), 0, stream>>>(c_lf, ws_lf, mean_lf, rstd_lf, wp_lf, bs_lf, yl);

  // ada convs (MFMA), bf16 NHWC out, lrelu
  k_conv_mfma<7, false, false, false><<<dim3(1024), dim3(256), 0, stream>>>(
      yh, nullptr, pk_adah, nullptr, ada_h_b, hfA);
  k_conv_mfma<6, false, false, false><<<dim3(256), dim3(256), 0, stream>>>(
      yl, nullptr, pk_adal, nullptr, ada_l_b, lfA);

  // avgpool hf (vectorized)
  k_pool_nhwc<<<dim3(2048), dim3(256), 0, stream>>>(hfA, hfP);

  // fused output convs (MFMA), f32 NCHW out, lrelu
  k_conv_mfma<7, true, true, true><<<dim3(1024), dim3(256), 0, stream>>>(
      hfA, lfA, pk_h2h, pk_l2h, nullptr, out_hf);
  k_conv_mfma<6, true, false, true><<<dim3(256), dim3(256), 0, stream>>>(
      lfA, hfP, pk_l2l, pk_h2l, nullptr, out_lf);
}